// Round 17
// baseline (135.313 us; speedup 1.0000x reference)
//
#include <hip/hip_runtime.h>
#include <hip/hip_bf16.h>

// Problem constants (B,C,H,W)=(8,256,32,32), heads=8, head_dim=32
#define BB 8
#define CC 256
#define NPIX 1024          // H*W
#define NH 8
#define HD 32
#define QKVO 768           // 3*256
#define EPS 1e-5f

typedef __attribute__((ext_vector_type(4)))  float floatx4;
typedef __attribute__((ext_vector_type(16))) float floatx16;
typedef __attribute__((ext_vector_type(8)))  short bf16x8;

// PROBE ROUND: ln_qkv x6, attn_proj x3 (idempotent repeats, laundered
// pointers) so both kernels surface above the 40us fill floor with counters.

// ---------------------------------------------------------------- weight prep: f32 row-major -> bf16 frag order
__global__ __launch_bounds__(256) void w_prep(const float* __restrict__ wq,
                                              const float* __restrict__ wp,
                                              __hip_bfloat16* __restrict__ wqf,
                                              __hip_bfloat16* __restrict__ wpf) {
    int idx = blockIdx.x * 256 + threadIdx.x;          // 0..32767
    const float* src;
    __hip_bfloat16* dst;
    int n;
    if (idx < 24576) { src = wq; dst = wqf; n = idx; }           // 48*8*64
    else             { src = wp; dst = wpf; n = idx - 24576; }   // 16*8*64
    const int lane = n & 63, kks = (n >> 6) & 7, tile = n >> 9;
    const int row = tile * 16 + (lane & 15);
    const int col = kks * 32 + (lane >> 4) * 8;
    const float* s = src + (size_t)row * CC + col;
    union { bf16x8 v; __hip_bfloat16 h[8]; } pk;
    #pragma unroll
    for (int j = 0; j < 8; ++j) pk.h[j] = __float2bfloat16(s[j]);
    *(bf16x8*)(dst + (size_t)n * 8) = pk.v;
}

// ---------------------------------------------------------------- fused LN + QKV GEMM (PROBE x6)
__global__ __launch_bounds__(512) void ln_qkv(const float* __restrict__ x_in,
                                              const float* __restrict__ gamma,
                                              const float* __restrict__ beta,
                                              const __hip_bfloat16* __restrict__ wqf_in,
                                              const float* __restrict__ bq,
                                              __hip_bfloat16* __restrict__ qf_in,
                                              __hip_bfloat16* __restrict__ kf_in,
                                              __hip_bfloat16* __restrict__ vf_in) {
    __shared__ short xbn[16 * 256];      // 8 KB normalized tile, swizzled
    __shared__ float s_part[32][17];
    __shared__ float q_part[32][17];
    __shared__ float s_mu[16], s_rs[16];

    const int tid  = threadIdx.x;
    const int P0   = blockIdx.x * 16;    // global pixel base (16 | 1024)
    const int b    = P0 >> 10;
    const int nloc = tid & 15;           // pixel within tile
    const int g    = tid >> 4;           // 0..31 channel group (8 ch each)
    const int w = tid >> 6, lane = tid & 63, lr = lane & 15, lg = lane >> 4;

    for (int rep = 0; rep < 6; ++rep) {
        // launder: forces full recompute each rep (no cross-rep CSE)
        const float* x = x_in;
        const __hip_bfloat16* wqf = wqf_in;
        __hip_bfloat16* qf = qf_in;
        __hip_bfloat16* kf = kf_in;
        __hip_bfloat16* vf = vf_in;
        asm volatile("" : "+r"(x), "+r"(wqf), "+r"(qf), "+r"(kf), "+r"(vf));
        __syncthreads();                 // protect LDS reuse across reps

        const float* xb = x + (size_t)b * CC * NPIX + (P0 & 1023);

        float vals[8];
        float s = 0.f, s2 = 0.f;
        #pragma unroll
        for (int j = 0; j < 8; ++j) {
            float v = xb[(size_t)(g * 8 + j) * NPIX + nloc];
            vals[j] = v; s += v; s2 += v * v;
        }
        s_part[g][nloc] = s; q_part[g][nloc] = s2;
        __syncthreads();
        if (tid < 16) {
            float ss = 0.f, qq = 0.f;
            #pragma unroll
            for (int k = 0; k < 32; ++k) { ss += s_part[k][tid]; qq += q_part[k][tid]; }
            float mu  = ss * (1.f / CC);
            float var = qq * (1.f / CC) - mu * mu;
            s_mu[tid] = mu; s_rs[tid] = rsqrtf(var + EPS);
        }
        __syncthreads();
        {
            const float mu = s_mu[nloc], rs = s_rs[nloc];
            union { bf16x8 v; unsigned short us[8]; } pk;
            #pragma unroll
            for (int j = 0; j < 8; ++j) {
                int c = g * 8 + j;
                pk.us[j] = __bfloat16_as_ushort(__float2bfloat16((vals[j] - mu) * rs * gamma[c] + beta[c]));
            }
            int idx = (nloc * 256 + g * 8) ^ (nloc << 3);
            *(bf16x8*)(&xbn[idx]) = pk.v;
        }
        __syncthreads();

        const int otb = w * 6;                  // 6 o-tiles per wave
        floatx4 acc[6] = {};
        for (int kks = 0; kks < 8; ++kks) {
            const int aidx = (lr * 256 + kks * 32 + lg * 8) ^ (lr << 3);
            bf16x8 a = *(const bf16x8*)(&xbn[aidx]);
            #pragma unroll
            for (int nt = 0; nt < 6; ++nt) {
                bf16x8 bfr = *(const bf16x8*)(wqf + (((size_t)(otb + nt) * 8 + kks) * 64 + lane) * 8);
                acc[nt] = __builtin_amdgcn_mfma_f32_16x16x32_bf16(a, bfr, acc[nt], 0, 0, 0);
            }
        }
        const float QSCALE = 0.25503495f;       // 0.17677669529663689 * 1.4426950408889634
        const int mb32   = (P0 & 16) + lg * 4;  // m base within the 32-pixel frag tile
        const int tile32 = (P0 & 1023) >> 5;    // 32-pixel tile within image
        #pragma unroll
        for (int nt = 0; nt < 6; ++nt) {
            const int o = (otb + nt) * 16 + lr;
            const int h = o / 96, om = o % 96;  // uniform per nt across the 16-lane run
            const float bias = bq[o];
            const size_t fb = (size_t)((b * NH + h) * 32 + tile32) * 1024;
            if (om < 64) {                      // Q or K: 4 scalar 2B stores
                const int d = om & 31;
                const bool isq = (om < 32);
                __hip_bfloat16* dst = (isq ? qf : kf);
                const float sc = isq ? QSCALE : 1.0f;
                const int off = (d >> 4) * 512 + ((d >> 3) & 1) * 256 + (d & 7);
                #pragma unroll
                for (int r = 0; r < 4; ++r)
                    dst[fb + off + (size_t)(mb32 + r) * 8] = __float2bfloat16((acc[nt][r] + bias) * sc);
            } else {                            // V: 4 consecutive m -> one uint2 store
                const int d = om - 64;
                const int half = mb32 >> 4, hi2 = (mb32 >> 3) & 1, j0 = mb32 & 7;
                union { unsigned short us[4]; uint2 u; } pv;
                #pragma unroll
                for (int r = 0; r < 4; ++r)
                    pv.us[r] = __bfloat16_as_ushort(__float2bfloat16(acc[nt][r] + bias));
                *(uint2*)(vf + fb + half * 512 + (d + 32 * hi2) * 8 + j0) = pv.u;
            }
        }
    }
}

// ---------------------------------------------------------------- fused attention + proj + residual (PROBE x3)
__global__ __launch_bounds__(1024, 4) void attn_proj(const __hip_bfloat16* __restrict__ qf_in,
                                                     const __hip_bfloat16* __restrict__ kf_in,
                                                     const __hip_bfloat16* __restrict__ vf_in,
                                                     const __hip_bfloat16* __restrict__ wpf_in,
                                                     const float* __restrict__ bp,
                                                     const float* __restrict__ x_in,
                                                     float* __restrict__ out_in) {
    __shared__ __align__(16) char smem_raw[34816 + 16384];   // m_lds(+ts alias) | o_lds
    float (*m_lds)[64][17] = (float (*)[64][17]) smem_raw;   // [8 heads][64][17]
    __hip_bfloat16* o_lds  = (__hip_bfloat16*)(smem_raw + 34816);  // [2 nt][8 kks][64 lane][8]

    const int bid = blockIdx.x;
    const int b   = bid & 7;                 // XCD swizzle: batch -> XCD
    const int t32 = bid >> 3;                // 32-pixel tile (0..31)
    const int tid = threadIdx.x, w = tid >> 6, lane = tid & 63;
    const int lr = lane & 15, lg = lane >> 4;
    const int lc = lane & 31, hi = lane >> 5;
    const int h  = w >> 1;                   // head (0..7)
    const int mh = w & 1;                    // KV half
    const int bh = b * NH + h;

    for (int rep = 0; rep < 3; ++rep) {
        const __hip_bfloat16* qf = qf_in;
        const __hip_bfloat16* kf = kf_in;
        const __hip_bfloat16* vf = vf_in;
        const __hip_bfloat16* wpf = wpf_in;
        const float* x = x_in;
        float* out = out_in;
        asm volatile("" : "+r"(qf), "+r"(kf), "+r"(vf), "+r"(wpf), "+r"(x), "+r"(out));
        __syncthreads();                     // protect LDS reuse across reps

        // ---- attention phase
        const __hip_bfloat16* qb = qf + (size_t)(bh * 32 + t32) * 1024;
        bf16x8 q0 = *(const bf16x8*)(qb + lane * 8);
        bf16x8 q1 = *(const bf16x8*)(qb + 512 + lane * 8);

        const __hip_bfloat16* kb = kf + (size_t)(bh * 32 + mh * 16) * 1024 + lane * 8;
        const __hip_bfloat16* vb = vf + (size_t)(bh * 32 + mh * 16) * 1024 + lane * 8;

        floatx16 oacc = {0.f,0.f,0.f,0.f,0.f,0.f,0.f,0.f,0.f,0.f,0.f,0.f,0.f,0.f,0.f,0.f};
        float ls0 = 0.f, ls1 = 0.f, ls2 = 0.f, ls3 = 0.f;

        #pragma unroll 4
        for (int t = 0; t < 16; ++t) {
            bf16x8 k0 = *(const bf16x8*)(kb + t * 1024);
            bf16x8 k1 = *(const bf16x8*)(kb + t * 1024 + 512);
            bf16x8 v0 = *(const bf16x8*)(vb + t * 1024);
            bf16x8 v1 = *(const bf16x8*)(vb + t * 1024 + 512);

            floatx16 st = {0.f,0.f,0.f,0.f,0.f,0.f,0.f,0.f,0.f,0.f,0.f,0.f,0.f,0.f,0.f,0.f};
            __builtin_amdgcn_s_setprio(1);
            st = __builtin_amdgcn_mfma_f32_32x32x16_bf16(k0, q0, st, 0, 0, 0);
            st = __builtin_amdgcn_mfma_f32_32x32x16_bf16(k1, q1, st, 0, 0, 0);
            __builtin_amdgcn_s_setprio(0);
            float p[16];
            #pragma unroll
            for (int r = 0; r < 16; ++r) p[r] = __builtin_amdgcn_exp2f(st[r]);   // raw v_exp_f32
            ls0 += p[0] + p[4] + p[8]  + p[12];
            ls1 += p[1] + p[5] + p[9]  + p[13];
            ls2 += p[2] + p[6] + p[10] + p[14];
            ls3 += p[3] + p[7] + p[11] + p[15];
            unsigned int wpk[8];
            #pragma unroll
            for (int k2 = 0; k2 < 8; ++k2)
                asm("v_cvt_pk_bf16_f32 %0, %1, %2" : "=v"(wpk[k2]) : "v"(p[2*k2]), "v"(p[2*k2+1]));
            asm("v_permlane32_swap_b32 %0, %1" : "+v"(wpk[0]), "+v"(wpk[2]));
            asm("v_permlane32_swap_b32 %0, %1" : "+v"(wpk[1]), "+v"(wpk[3]));
            asm("v_permlane32_swap_b32 %0, %1" : "+v"(wpk[4]), "+v"(wpk[6]));
            asm("v_permlane32_swap_b32 %0, %1" : "+v"(wpk[5]), "+v"(wpk[7]));
            union { bf16x8 v; unsigned int u[4]; } pb0, pb1;
            pb0.u[0] = wpk[0]; pb0.u[1] = wpk[1]; pb0.u[2] = wpk[2]; pb0.u[3] = wpk[3];
            pb1.u[0] = wpk[4]; pb1.u[1] = wpk[5]; pb1.u[2] = wpk[6]; pb1.u[3] = wpk[7];
            __builtin_amdgcn_s_setprio(1);
            oacc = __builtin_amdgcn_mfma_f32_32x32x16_bf16(v0, pb0.v, oacc, 0, 0, 0);
            oacc = __builtin_amdgcn_mfma_f32_32x32x16_bf16(v1, pb1.v, oacc, 0, 0, 0);
            __builtin_amdgcn_s_setprio(0);
        }
        float lsum = (ls0 + ls1) + (ls2 + ls3);

        // ---- 2-way KV merge per head (pure sums)
        if (mh == 1) {
            #pragma unroll
            for (int r = 0; r < 16; ++r) m_lds[h][lane][r] = oacc[r];
            m_lds[h][lane][16] = lsum;
        }
        __syncthreads();
        if (mh == 0) {
            #pragma unroll
            for (int r = 0; r < 16; ++r) oacc[r] += m_lds[h][lane][r];
            lsum += m_lds[h][lane][16];
            lsum += __shfl_xor(lsum, 32);
            float inv = 1.0f / lsum;
            float (*ts)[33] = (float (*)[33]) &m_lds[h][0][0];
            #pragma unroll
            for (int r = 0; r < 16; ++r) {
                int d = (r & 3) + 8 * (r >> 2) + 4 * hi;
                ts[lc][d] = oacc[r] * inv;
            }
        }
        __syncthreads();
        if (mh == 0) {
            float (*ts)[33] = (float (*)[33]) &m_lds[h][0][0];
            const int q = lane >> 4, nl = lane & 15;
            #pragma unroll
            for (int nt = 0; nt < 2; ++nt) {
                union { __hip_bfloat16 h16[8]; uint4 u4; } ov;
                #pragma unroll
                for (int j = 0; j < 8; ++j)
                    ov.h16[j] = __float2bfloat16(ts[nt * 16 + nl][q * 8 + j]);
                *(uint4*)(o_lds + (((size_t)nt * 8 + h) * 64 + lane) * 8) = ov.u4;
            }
        }
        __syncthreads();

        // ---- proj phase: wave w = c-tile (0..15)
        {
            const int ct = w;
            floatx4 acc2[2] = {};
            for (int kks = 0; kks < 8; ++kks) {
                bf16x8 aa = *(const bf16x8*)(wpf + (((size_t)ct * 8 + kks) * 64 + lane) * 8);
                #pragma unroll
                for (int nt = 0; nt < 2; ++nt) {
                    bf16x8 bb = *(const bf16x8*)(o_lds + (((size_t)nt * 8 + kks) * 64 + lane) * 8);
                    acc2[nt] = __builtin_amdgcn_mfma_f32_16x16x32_bf16(aa, bb, acc2[nt], 0, 0, 0);
                }
            }
            #pragma unroll
            for (int nt = 0; nt < 2; ++nt)
                #pragma unroll
                for (int r = 0; r < 4; ++r) {
                    int c = ct * 16 + lg * 4 + r;
                    int n = t32 * 32 + nt * 16 + lr;
                    size_t idx = ((size_t)b * CC + c) * NPIX + n;
                    out[idx] = acc2[nt][r] + bp[c] + x[idx];
                }
        }
    }
}

// ---------------------------------------------------------------- launch
extern "C" void kernel_launch(void* const* d_in, const int* in_sizes, int n_in,
                              void* d_out, int out_size, void* d_ws, size_t ws_size,
                              hipStream_t stream) {
    const float* x      = (const float*)d_in[0];
    const float* gamma  = (const float*)d_in[1];
    const float* beta   = (const float*)d_in[2];
    const float* w_qkv  = (const float*)d_in[3];
    const float* b_qkv  = (const float*)d_in[4];
    const float* w_proj = (const float*)d_in[5];
    const float* b_proj = (const float*)d_in[6];
    float* out = (float*)d_out;

    char* ws = (char*)d_ws;
    __hip_bfloat16* qfb  = (__hip_bfloat16*)(ws);                            // 4 MB
    __hip_bfloat16* kfb  = (__hip_bfloat16*)(ws + (4  << 20));               // 4 MB
    __hip_bfloat16* vfb  = (__hip_bfloat16*)(ws + (8  << 20));               // 4 MB
    __hip_bfloat16* wqf  = (__hip_bfloat16*)(ws + (12 << 20));               // 384 KB frag
    __hip_bfloat16* wpf  = (__hip_bfloat16*)(ws + (12 << 20) + (512 << 10)); // 128 KB frag

    w_prep<<<128, 256, 0, stream>>>(w_qkv, w_proj, wqf, wpf);
    ln_qkv<<<BB * NPIX / 16, 512, 0, stream>>>(x, gamma, beta, wqf, b_qkv, qfb, kfb, vfb);
    attn_proj<<<BB * 32, 1024, 0, stream>>>(qfb, kfb, vfb, wpf, b_proj, x, out);
}

// Round 18
// 45.289 us; speedup vs baseline: 2.9878x; 2.9878x over previous
//
#include <hip/hip_runtime.h>
#include <hip/hip_bf16.h>

// Problem constants (B,C,H,W)=(8,256,32,32), heads=8, head_dim=32
#define BB 8
#define CC 256
#define NPIX 1024          // H*W
#define NH 8
#define HD 32
#define QKVO 768           // 3*256
#define EPS 1e-5f

typedef __attribute__((ext_vector_type(4)))  float floatx4;
typedef __attribute__((ext_vector_type(16))) float floatx16;
typedef __attribute__((ext_vector_type(8)))  short bf16x8;

// Q/K/V frag layout (per (bh,tile32) block of 1024 bf16 = [sub2][lane64][elem8]):
//   Q (B-op): lane = (n&31) + 32*((d>>3)&1), sub = d>>4,        elem = d&7
//     -> linear addr within block: (d>>3)*256 + m*8 + (d&7)
//   K (A-op): same mapping as Q
//   V (A-op): lane = d + 32*((m&15)>>3), sub = (m&31)>>4, elem = m&7
// Q pre-scaled by head_dim^-0.5 * log2(e) so softmax is p = 2^st.
// Weight frags: wf[((tile*8+kks)*64+lane)*8+j] = W[tile*16+(lane&15)][kks*32+(lane>>4)*8+j]

// ---------------------------------------------------------------- weight prep: f32 row-major -> bf16 frag order
__global__ __launch_bounds__(256) void w_prep(const float* __restrict__ wq,
                                              const float* __restrict__ wp,
                                              __hip_bfloat16* __restrict__ wqf,
                                              __hip_bfloat16* __restrict__ wpf) {
    int idx = blockIdx.x * 256 + threadIdx.x;          // 0..32767
    const float* src;
    __hip_bfloat16* dst;
    int n;
    if (idx < 24576) { src = wq; dst = wqf; n = idx; }           // 48*8*64
    else             { src = wp; dst = wpf; n = idx - 24576; }   // 16*8*64
    const int lane = n & 63, kks = (n >> 6) & 7, tile = n >> 9;
    const int row = tile * 16 + (lane & 15);
    const int col = kks * 32 + (lane >> 4) * 8;
    const float* s = src + (size_t)row * CC + col;
    union { bf16x8 v; __hip_bfloat16 h[8]; } pk;
    #pragma unroll
    for (int j = 0; j < 8; ++j) pk.h[j] = __float2bfloat16(s[j]);
    *(bf16x8*)(dst + (size_t)n * 8) = pk.v;
}

// ---------------------------------------------------------------- fused LN + QKV GEMM -> fragment buffers
// 16-pixel tile per block, grid 512 (2 blocks/CU). Epilogue v2: Q/K staged
// through LDS (chunk-linear) then written fully coalesced -- removes the
// 16-scattered-2B-stores-per-thread write gather (probe: 75% stall).
__global__ __launch_bounds__(512) void ln_qkv(const float* __restrict__ x,
                                              const float* __restrict__ gamma,
                                              const float* __restrict__ beta,
                                              const __hip_bfloat16* __restrict__ wqf,
                                              const float* __restrict__ bq,
                                              __hip_bfloat16* __restrict__ qf,
                                              __hip_bfloat16* __restrict__ kf,
                                              __hip_bfloat16* __restrict__ vf) {
    __shared__ short xbn[16 * 256];                 // 8 KB normalized tile, swizzled
    __shared__ float s_part[32][17];
    __shared__ float q_part[32][17];
    __shared__ float s_mu[16], s_rs[16];
    __shared__ __hip_bfloat16 qk_stage[64 * 128];   // 16 KB: chunk-linear Q/K stage

    const int tid  = threadIdx.x;
    const int P0   = blockIdx.x * 16;    // global pixel base (16 | 1024)
    const int b    = P0 >> 10;
    const int nloc = tid & 15;           // pixel within tile
    const int g    = tid >> 4;           // 0..31 channel group (8 ch each)
    const float* xb = x + (size_t)b * CC * NPIX + (P0 & 1023);

    // ---- Phase A: stats; each thread loads its 8 channels, keeps them
    float vals[8];
    float s = 0.f, s2 = 0.f;
    #pragma unroll
    for (int j = 0; j < 8; ++j) {
        float v = xb[(size_t)(g * 8 + j) * NPIX + nloc];
        vals[j] = v; s += v; s2 += v * v;
    }
    s_part[g][nloc] = s; q_part[g][nloc] = s2;
    __syncthreads();
    if (tid < 16) {
        float ss = 0.f, qq = 0.f;
        #pragma unroll
        for (int k = 0; k < 32; ++k) { ss += s_part[k][tid]; qq += q_part[k][tid]; }
        float mu  = ss * (1.f / CC);
        float var = qq * (1.f / CC) - mu * mu;
        s_mu[tid] = mu; s_rs[tid] = rsqrtf(var + EPS);
    }
    __syncthreads();

    // ---- Phase B: normalize from registers -> swizzled LDS bf16
    {
        const float mu = s_mu[nloc], rs = s_rs[nloc];
        union { bf16x8 v; unsigned short us[8]; } pk;
        #pragma unroll
        for (int j = 0; j < 8; ++j) {
            int c = g * 8 + j;
            pk.us[j] = __bfloat16_as_ushort(__float2bfloat16((vals[j] - mu) * rs * gamma[c] + beta[c]));
        }
        int idx = (nloc * 256 + g * 8) ^ (nloc << 3);
        *(bf16x8*)(&xbn[idx]) = pk.v;
    }
    __syncthreads();

    // ---- Phase C: GEMM 16 x 768 x 256, weights from frag buffer (contiguous)
    const int w = tid >> 6, lane = tid & 63, lr = lane & 15, lg = lane >> 4;
    const int otb = w * 6;                  // 6 o-tiles per wave (one head: h = w)
    floatx4 acc[6] = {};
    for (int kks = 0; kks < 8; ++kks) {
        const int aidx = (lr * 256 + kks * 32 + lg * 8) ^ (lr << 3);
        bf16x8 a = *(const bf16x8*)(&xbn[aidx]);
        #pragma unroll
        for (int nt = 0; nt < 6; ++nt) {
            bf16x8 bfr = *(const bf16x8*)(wqf + (((size_t)(otb + nt) * 8 + kks) * 64 + lane) * 8);
            acc[nt] = __builtin_amdgcn_mfma_f32_16x16x32_bf16(a, bfr, acc[nt], 0, 0, 0);
        }
    }

    // ---- epilogue v2: Q/K -> LDS stage; V direct (1KB-regional uint2)
    // chunk = (h*2 + isK)*4 + (d>>3); LDS idx = chunk*128 + mloc*8 + (d&7)
    const float QSCALE = 0.25503495f;       // 0.17677669529663689 * 1.4426950408889634
    const int mb32   = (P0 & 16) + lg * 4;  // m base within the 32-pixel frag tile
    const int mloc0  = lg * 4;              // m-local within this block's 16 rows
    const int tile32 = (P0 & 1023) >> 5;    // 32-pixel tile within image
    #pragma unroll
    for (int nt = 0; nt < 6; ++nt) {
        const int o = (otb + nt) * 16 + lr;
        const int h = o / 96, om = o % 96;  // uniform per nt across the 16-lane run
        const float bias = bq[o];
        if (om < 64) {                      // Q or K -> LDS stage (scattered 2B, cheap)
            const int d = om & 31;
            const bool isq = (om < 32);
            const float sc = isq ? QSCALE : 1.0f;
            const int chunk = (h * 2 + (isq ? 0 : 1)) * 4 + (d >> 3);
            #pragma unroll
            for (int r = 0; r < 4; ++r)
                qk_stage[chunk * 128 + (mloc0 + r) * 8 + (d & 7)] =
                    __float2bfloat16((acc[nt][r] + bias) * sc);
        } else {                            // V: 4 consecutive m -> one uint2 store
            const int d = om - 64;
            const size_t fb = (size_t)((b * NH + h) * 32 + tile32) * 1024;
            const int half = mb32 >> 4, hi2 = (mb32 >> 3) & 1, j0 = mb32 & 7;
            union { unsigned short us[4]; uint2 u; } pv;
            #pragma unroll
            for (int r = 0; r < 4; ++r)
                pv.us[r] = __bfloat16_as_ushort(__float2bfloat16(acc[nt][r] + bias));
            *(uint2*)(vf + fb + half * 512 + (d + 32 * hi2) * 8 + j0) = pv.u;
        }
    }
    __syncthreads();

    // ---- coalesced Q/K writeout: thread tid -> chunk tid>>3, 32B contiguous
    {
        const int chunk = tid >> 3;             // 0..63
        const int off   = (tid & 7) * 16;       // 16 bf16 per thread
        const int h     = chunk >> 3;
        const int isK   = (chunk >> 2) & 1;
        const int g3    = chunk & 3;
        const size_t fb = (size_t)((b * NH + h) * 32 + tile32) * 1024;
        __hip_bfloat16* base = (isK ? kf : qf) + fb + g3 * 256 + (size_t)(P0 & 16) * 8;
        bf16x8 v0 = *(const bf16x8*)(&qk_stage[chunk * 128 + off]);
        bf16x8 v1 = *(const bf16x8*)(&qk_stage[chunk * 128 + off + 8]);
        *(bf16x8*)(base + off)     = v0;
        *(bf16x8*)(base + off + 8) = v1;
    }
}

// ---------------------------------------------------------------- fused attention + proj + residual
// Block = (b, 32-pixel tile): 16 waves = 8 heads x 2 KV-halves; grid 256.
// launch_bounds(1024,4): 128 VGPR budget for deep ILP (unroll 4 keeps 2-3
// KV tiles of loads in flight). Verbatim from R16 (passing, 45.1us total).
__global__ __launch_bounds__(1024, 4) void attn_proj(const __hip_bfloat16* __restrict__ qf,
                                                     const __hip_bfloat16* __restrict__ kf,
                                                     const __hip_bfloat16* __restrict__ vf,
                                                     const __hip_bfloat16* __restrict__ wpf,
                                                     const float* __restrict__ bp,
                                                     const float* __restrict__ x,
                                                     float* __restrict__ out) {
    __shared__ __align__(16) char smem_raw[34816 + 16384];   // m_lds(+ts alias) | o_lds
    float (*m_lds)[64][17] = (float (*)[64][17]) smem_raw;   // [8 heads][64][17]
    __hip_bfloat16* o_lds  = (__hip_bfloat16*)(smem_raw + 34816);  // [2 nt][8 kks][64 lane][8]

    const int bid = blockIdx.x;
    const int b   = bid & 7;                 // XCD swizzle: batch -> XCD
    const int t32 = bid >> 3;                // 32-pixel tile (0..31)
    const int tid = threadIdx.x, w = tid >> 6, lane = tid & 63;
    const int lr = lane & 15, lg = lane >> 4;
    const int lc = lane & 31, hi = lane >> 5;
    const int h  = w >> 1;                   // head (0..7)
    const int mh = w & 1;                    // KV half
    const int bh = b * NH + h;

    // ---- attention phase
    const __hip_bfloat16* qb = qf + (size_t)(bh * 32 + t32) * 1024;
    bf16x8 q0 = *(const bf16x8*)(qb + lane * 8);
    bf16x8 q1 = *(const bf16x8*)(qb + 512 + lane * 8);

    const __hip_bfloat16* kb = kf + (size_t)(bh * 32 + mh * 16) * 1024 + lane * 8;
    const __hip_bfloat16* vb = vf + (size_t)(bh * 32 + mh * 16) * 1024 + lane * 8;

    floatx16 oacc = {0.f,0.f,0.f,0.f,0.f,0.f,0.f,0.f,0.f,0.f,0.f,0.f,0.f,0.f,0.f,0.f};
    float ls0 = 0.f, ls1 = 0.f, ls2 = 0.f, ls3 = 0.f;

    #pragma unroll 4
    for (int t = 0; t < 16; ++t) {
        bf16x8 k0 = *(const bf16x8*)(kb + t * 1024);
        bf16x8 k1 = *(const bf16x8*)(kb + t * 1024 + 512);
        bf16x8 v0 = *(const bf16x8*)(vb + t * 1024);
        bf16x8 v1 = *(const bf16x8*)(vb + t * 1024 + 512);

        floatx16 st = {0.f,0.f,0.f,0.f,0.f,0.f,0.f,0.f,0.f,0.f,0.f,0.f,0.f,0.f,0.f,0.f};
        __builtin_amdgcn_s_setprio(1);
        st = __builtin_amdgcn_mfma_f32_32x32x16_bf16(k0, q0, st, 0, 0, 0);
        st = __builtin_amdgcn_mfma_f32_32x32x16_bf16(k1, q1, st, 0, 0, 0);
        __builtin_amdgcn_s_setprio(0);
        float p[16];
        #pragma unroll
        for (int r = 0; r < 16; ++r) p[r] = __builtin_amdgcn_exp2f(st[r]);   // raw v_exp_f32
        ls0 += p[0] + p[4] + p[8]  + p[12];
        ls1 += p[1] + p[5] + p[9]  + p[13];
        ls2 += p[2] + p[6] + p[10] + p[14];
        ls3 += p[3] + p[7] + p[11] + p[15];
        unsigned int wpk[8];
        #pragma unroll
        for (int k2 = 0; k2 < 8; ++k2)
            asm("v_cvt_pk_bf16_f32 %0, %1, %2" : "=v"(wpk[k2]) : "v"(p[2*k2]), "v"(p[2*k2+1]));
        asm("v_permlane32_swap_b32 %0, %1" : "+v"(wpk[0]), "+v"(wpk[2]));
        asm("v_permlane32_swap_b32 %0, %1" : "+v"(wpk[1]), "+v"(wpk[3]));
        asm("v_permlane32_swap_b32 %0, %1" : "+v"(wpk[4]), "+v"(wpk[6]));
        asm("v_permlane32_swap_b32 %0, %1" : "+v"(wpk[5]), "+v"(wpk[7]));
        union { bf16x8 v; unsigned int u[4]; } pb0, pb1;
        pb0.u[0] = wpk[0]; pb0.u[1] = wpk[1]; pb0.u[2] = wpk[2]; pb0.u[3] = wpk[3];
        pb1.u[0] = wpk[4]; pb1.u[1] = wpk[5]; pb1.u[2] = wpk[6]; pb1.u[3] = wpk[7];
        __builtin_amdgcn_s_setprio(1);
        oacc = __builtin_amdgcn_mfma_f32_32x32x16_bf16(v0, pb0.v, oacc, 0, 0, 0);
        oacc = __builtin_amdgcn_mfma_f32_32x32x16_bf16(v1, pb1.v, oacc, 0, 0, 0);
        __builtin_amdgcn_s_setprio(0);
    }
    float lsum = (ls0 + ls1) + (ls2 + ls3);

    // ---- 2-way KV merge per head (pure sums)
    if (mh == 1) {
        #pragma unroll
        for (int r = 0; r < 16; ++r) m_lds[h][lane][r] = oacc[r];
        m_lds[h][lane][16] = lsum;
    }
    __syncthreads();
    if (mh == 0) {
        #pragma unroll
        for (int r = 0; r < 16; ++r) oacc[r] += m_lds[h][lane][r];
        lsum += m_lds[h][lane][16];
        lsum += __shfl_xor(lsum, 32);
        float inv = 1.0f / lsum;
        float (*ts)[33] = (float (*)[33]) &m_lds[h][0][0];
        #pragma unroll
        for (int r = 0; r < 16; ++r) {
            int d = (r & 3) + 8 * (r >> 2) + 4 * hi;
            ts[lc][d] = oacc[r] * inv;
        }
    }
    __syncthreads();
    if (mh == 0) {
        float (*ts)[33] = (float (*)[33]) &m_lds[h][0][0];
        const int q = lane >> 4, nl = lane & 15;
        #pragma unroll
        for (int nt = 0; nt < 2; ++nt) {
            union { __hip_bfloat16 h16[8]; uint4 u4; } ov;
            #pragma unroll
            for (int j = 0; j < 8; ++j)
                ov.h16[j] = __float2bfloat16(ts[nt * 16 + nl][q * 8 + j]);
            *(uint4*)(o_lds + (((size_t)nt * 8 + h) * 64 + lane) * 8) = ov.u4;
        }
    }
    __syncthreads();

    // ---- proj phase: wave w = c-tile (0..15); output 32 pixels x 16 channels
    {
        const int ct = w;
        floatx4 acc2[2] = {};
        for (int kks = 0; kks < 8; ++kks) {
            bf16x8 aa = *(const bf16x8*)(wpf + (((size_t)ct * 8 + kks) * 64 + lane) * 8);
            #pragma unroll
            for (int nt = 0; nt < 2; ++nt) {
                bf16x8 bb = *(const bf16x8*)(o_lds + (((size_t)nt * 8 + kks) * 64 + lane) * 8);
                acc2[nt] = __builtin_amdgcn_mfma_f32_16x16x32_bf16(aa, bb, acc2[nt], 0, 0, 0);
            }
        }
        #pragma unroll
        for (int nt = 0; nt < 2; ++nt)
            #pragma unroll
            for (int r = 0; r < 4; ++r) {
                int c = ct * 16 + lg * 4 + r;
                int n = t32 * 32 + nt * 16 + lr;
                size_t idx = ((size_t)b * CC + c) * NPIX + n;
                out[idx] = acc2[nt][r] + bp[c] + x[idx];
            }
    }
}

// ---------------------------------------------------------------- launch
extern "C" void kernel_launch(void* const* d_in, const int* in_sizes, int n_in,
                              void* d_out, int out_size, void* d_ws, size_t ws_size,
                              hipStream_t stream) {
    const float* x      = (const float*)d_in[0];
    const float* gamma  = (const float*)d_in[1];
    const float* beta   = (const float*)d_in[2];
    const float* w_qkv  = (const float*)d_in[3];
    const float* b_qkv  = (const float*)d_in[4];
    const float* w_proj = (const float*)d_in[5];
    const float* b_proj = (const float*)d_in[6];
    float* out = (float*)d_out;

    char* ws = (char*)d_ws;
    __hip_bfloat16* qfb  = (__hip_bfloat16*)(ws);                            // 4 MB
    __hip_bfloat16* kfb  = (__hip_bfloat16*)(ws + (4  << 20));               // 4 MB
    __hip_bfloat16* vfb  = (__hip_bfloat16*)(ws + (8  << 20));               // 4 MB
    __hip_bfloat16* wqf  = (__hip_bfloat16*)(ws + (12 << 20));               // 384 KB frag
    __hip_bfloat16* wpf  = (__hip_bfloat16*)(ws + (12 << 20) + (512 << 10)); // 128 KB frag

    w_prep<<<128, 256, 0, stream>>>(w_qkv, w_proj, wqf, wpf);
    ln_qkv<<<BB * NPIX / 16, 512, 0, stream>>>(x, gamma, beta, wqf, b_qkv, qfb, kfb, vfb);
    attn_proj<<<BB * 32, 1024, 0, stream>>>(qfb, kfb, vfb, wpf, b_proj, x, out);
}

// Round 19
// 43.688 us; speedup vs baseline: 3.0973x; 1.0367x over previous
//
#include <hip/hip_runtime.h>
#include <hip/hip_bf16.h>

// Problem constants (B,C,H,W)=(8,256,32,32), heads=8, head_dim=32
#define BB 8
#define CC 256
#define NPIX 1024          // H*W
#define NH 8
#define HD 32
#define QKVO 768           // 3*256
#define EPS 1e-5f

typedef __attribute__((ext_vector_type(4)))  float floatx4;
typedef __attribute__((ext_vector_type(16))) float floatx16;
typedef __attribute__((ext_vector_type(8)))  short bf16x8;

// Q/K/V frag layout (per (bh,tile32) block of 1024 bf16 = [sub2][lane64][elem8]):
//   Q (B-op): lane = (n&31) + 32*((d>>3)&1), sub = d>>4,        elem = d&7
//     -> linear addr within block: (d>>3)*256 + m*8 + (d&7)
//   K (A-op): same mapping as Q
//   V (A-op): lane = d + 32*((m&15)>>3), sub = (m&31)>>4, elem = m&7
// Q pre-scaled by head_dim^-0.5 * log2(e) so softmax is p = 2^st.
// Weight frags: wf[((tile*8+kks)*64+lane)*8+j] = W[tile*16+(lane&15)][kks*32+(lane>>4)*8+j]

// ---------------------------------------------------------------- weight prep: f32 row-major -> bf16 frag order
__global__ __launch_bounds__(256) void w_prep(const float* __restrict__ wq,
                                              const float* __restrict__ wp,
                                              __hip_bfloat16* __restrict__ wqf,
                                              __hip_bfloat16* __restrict__ wpf) {
    int idx = blockIdx.x * 256 + threadIdx.x;          // 0..32767
    const float* src;
    __hip_bfloat16* dst;
    int n;
    if (idx < 24576) { src = wq; dst = wqf; n = idx; }           // 48*8*64
    else             { src = wp; dst = wpf; n = idx - 24576; }   // 16*8*64
    const int lane = n & 63, kks = (n >> 6) & 7, tile = n >> 9;
    const int row = tile * 16 + (lane & 15);
    const int col = kks * 32 + (lane >> 4) * 8;
    const float* s = src + (size_t)row * CC + col;
    union { bf16x8 v; __hip_bfloat16 h[8]; } pk;
    #pragma unroll
    for (int j = 0; j < 8; ++j) pk.h[j] = __float2bfloat16(s[j]);
    *(bf16x8*)(dst + (size_t)n * 8) = pk.v;
}

// ---------------------------------------------------------------- fused LN + QKV GEMM -> fragment buffers
// v3: 16-pixel tile, 1024 threads = 16 SKINNY waves (3 o-tiles each, acc=12
// VGPR) under launch_bounds(1024,8) -> VGPR<=64 -> 2 blocks/CU = 32 waves/CU
// (probe showed 21% occupancy / 75% stall at the old 8-fat-wave shape).
__global__ __launch_bounds__(1024, 8) void ln_qkv(const float* __restrict__ x,
                                                  const float* __restrict__ gamma,
                                                  const float* __restrict__ beta,
                                                  const __hip_bfloat16* __restrict__ wqf,
                                                  const float* __restrict__ bq,
                                                  __hip_bfloat16* __restrict__ qf,
                                                  __hip_bfloat16* __restrict__ kf,
                                                  __hip_bfloat16* __restrict__ vf) {
    __shared__ short xbn[16 * 256];                 // 8 KB normalized tile, swizzled
    __shared__ float s_part[64][17];
    __shared__ float q_part[64][17];
    __shared__ float s_mu[16], s_rs[16];
    __shared__ __hip_bfloat16 qk_stage[64 * 128];   // 16 KB: chunk-linear Q/K stage

    const int tid  = threadIdx.x;
    const int P0   = blockIdx.x * 16;    // global pixel base (16 | 1024)
    const int b    = P0 >> 10;
    const int nloc = tid & 15;           // pixel within tile
    const int g    = tid >> 4;           // 0..63 channel group (4 ch each)
    const float* xb = x + (size_t)b * CC * NPIX + (P0 & 1023);

    // ---- Phase A: stats; each thread loads its 4 channels, keeps them
    float vals[4];
    float s = 0.f, s2 = 0.f;
    #pragma unroll
    for (int j = 0; j < 4; ++j) {
        float v = xb[(size_t)(g * 4 + j) * NPIX + nloc];
        vals[j] = v; s += v; s2 += v * v;
    }
    s_part[g][nloc] = s; q_part[g][nloc] = s2;
    __syncthreads();
    if (tid < 16) {
        float ss = 0.f, qq = 0.f;
        #pragma unroll
        for (int k = 0; k < 64; ++k) { ss += s_part[k][tid]; qq += q_part[k][tid]; }
        float mu  = ss * (1.f / CC);
        float var = qq * (1.f / CC) - mu * mu;
        s_mu[tid] = mu; s_rs[tid] = rsqrtf(var + EPS);
    }
    __syncthreads();

    // ---- Phase B: normalize from registers -> swizzled LDS bf16 (uint2 store)
    {
        const float mu = s_mu[nloc], rs = s_rs[nloc];
        union { uint2 u; __hip_bfloat16 h[4]; } pk;
        #pragma unroll
        for (int j = 0; j < 4; ++j) {
            int c = g * 4 + j;
            pk.h[j] = __float2bfloat16((vals[j] - mu) * rs * gamma[c] + beta[c]);
        }
        int idx = (nloc * 256 + g * 4) ^ (nloc << 3);   // xor touches bits>=3: 8B store stays aligned
        *(uint2*)(&xbn[idx]) = pk.u;
    }
    __syncthreads();

    // ---- Phase C: GEMM 16 x 768 x 256; wave w owns 3 o-tiles (48 outputs)
    const int w = tid >> 6, lane = tid & 63, lr = lane & 15, lg = lane >> 4;
    const int otb = w * 3;
    floatx4 acc[3] = {};
    for (int kks = 0; kks < 8; ++kks) {
        const int aidx = (lr * 256 + kks * 32 + lg * 8) ^ (lr << 3);
        bf16x8 a = *(const bf16x8*)(&xbn[aidx]);
        #pragma unroll
        for (int nt = 0; nt < 3; ++nt) {
            bf16x8 bfr = *(const bf16x8*)(wqf + (((size_t)(otb + nt) * 8 + kks) * 64 + lane) * 8);
            acc[nt] = __builtin_amdgcn_mfma_f32_16x16x32_bf16(a, bfr, acc[nt], 0, 0, 0);
        }
    }

    // ---- epilogue: Q/K -> LDS stage (chunk-linear); V direct (1KB-regional uint2)
    const float QSCALE = 0.25503495f;       // 0.17677669529663689 * 1.4426950408889634
    const int mb32   = (P0 & 16) + lg * 4;  // m base within the 32-pixel frag tile
    const int mloc0  = lg * 4;              // m-local within this block's 16 rows
    const int tile32 = (P0 & 1023) >> 5;    // 32-pixel tile within image
    #pragma unroll
    for (int nt = 0; nt < 3; ++nt) {
        const int o = (otb + nt) * 16 + lr;
        const int h = o / 96, om = o % 96;  // uniform per nt across the 16-lane run
        const float bias = bq[o];
        if (om < 64) {                      // Q or K -> LDS stage
            const int d = om & 31;
            const bool isq = (om < 32);
            const float sc = isq ? QSCALE : 1.0f;
            const int chunk = (h * 2 + (isq ? 0 : 1)) * 4 + (d >> 3);
            #pragma unroll
            for (int r = 0; r < 4; ++r)
                qk_stage[chunk * 128 + (mloc0 + r) * 8 + (d & 7)] =
                    __float2bfloat16((acc[nt][r] + bias) * sc);
        } else {                            // V: 4 consecutive m -> one uint2 store
            const int d = om - 64;
            const size_t fb = (size_t)((b * NH + h) * 32 + tile32) * 1024;
            const int half = mb32 >> 4, hi2 = (mb32 >> 3) & 1, j0 = mb32 & 7;
            union { unsigned short us[4]; uint2 u; } pv;
            #pragma unroll
            for (int r = 0; r < 4; ++r)
                pv.us[r] = __bfloat16_as_ushort(__float2bfloat16(acc[nt][r] + bias));
            *(uint2*)(vf + fb + half * 512 + (d + 32 * hi2) * 8 + j0) = pv.u;
        }
    }
    __syncthreads();

    // ---- coalesced Q/K writeout: thread tid -> chunk tid>>4, one 16B store
    {
        const int chunk = tid >> 4;             // 0..63
        const int off   = (tid & 15) * 8;       // 8 bf16 per thread
        const int h     = chunk >> 3;
        const int isK   = (chunk >> 2) & 1;
        const int g3    = chunk & 3;
        const size_t fb = (size_t)((b * NH + h) * 32 + tile32) * 1024;
        __hip_bfloat16* base = (isK ? kf : qf) + fb + g3 * 256 + (size_t)(P0 & 16) * 8;
        *(bf16x8*)(base + off) = *(const bf16x8*)(&qk_stage[chunk * 128 + off]);
    }
}

// ---------------------------------------------------------------- fused attention + proj + residual
// Block = (b, 32-pixel tile): 16 waves = 8 heads x 2 KV-halves; grid 256.
// launch_bounds(1024,4): 128 VGPR budget for deep ILP (unroll 4 keeps 2-3
// KV tiles of loads in flight). Verbatim from R16/R18 (passing).
__global__ __launch_bounds__(1024, 4) void attn_proj(const __hip_bfloat16* __restrict__ qf,
                                                     const __hip_bfloat16* __restrict__ kf,
                                                     const __hip_bfloat16* __restrict__ vf,
                                                     const __hip_bfloat16* __restrict__ wpf,
                                                     const float* __restrict__ bp,
                                                     const float* __restrict__ x,
                                                     float* __restrict__ out) {
    __shared__ __align__(16) char smem_raw[34816 + 16384];   // m_lds(+ts alias) | o_lds
    float (*m_lds)[64][17] = (float (*)[64][17]) smem_raw;   // [8 heads][64][17]
    __hip_bfloat16* o_lds  = (__hip_bfloat16*)(smem_raw + 34816);  // [2 nt][8 kks][64 lane][8]

    const int bid = blockIdx.x;
    const int b   = bid & 7;                 // XCD swizzle: batch -> XCD
    const int t32 = bid >> 3;                // 32-pixel tile (0..31)
    const int tid = threadIdx.x, w = tid >> 6, lane = tid & 63;
    const int lr = lane & 15, lg = lane >> 4;
    const int lc = lane & 31, hi = lane >> 5;
    const int h  = w >> 1;                   // head (0..7)
    const int mh = w & 1;                    // KV half
    const int bh = b * NH + h;

    // ---- attention phase
    const __hip_bfloat16* qb = qf + (size_t)(bh * 32 + t32) * 1024;
    bf16x8 q0 = *(const bf16x8*)(qb + lane * 8);
    bf16x8 q1 = *(const bf16x8*)(qb + 512 + lane * 8);

    const __hip_bfloat16* kb = kf + (size_t)(bh * 32 + mh * 16) * 1024 + lane * 8;
    const __hip_bfloat16* vb = vf + (size_t)(bh * 32 + mh * 16) * 1024 + lane * 8;

    floatx16 oacc = {0.f,0.f,0.f,0.f,0.f,0.f,0.f,0.f,0.f,0.f,0.f,0.f,0.f,0.f,0.f,0.f};
    float ls0 = 0.f, ls1 = 0.f, ls2 = 0.f, ls3 = 0.f;

    #pragma unroll 4
    for (int t = 0; t < 16; ++t) {
        bf16x8 k0 = *(const bf16x8*)(kb + t * 1024);
        bf16x8 k1 = *(const bf16x8*)(kb + t * 1024 + 512);
        bf16x8 v0 = *(const bf16x8*)(vb + t * 1024);
        bf16x8 v1 = *(const bf16x8*)(vb + t * 1024 + 512);

        floatx16 st = {0.f,0.f,0.f,0.f,0.f,0.f,0.f,0.f,0.f,0.f,0.f,0.f,0.f,0.f,0.f,0.f};
        __builtin_amdgcn_s_setprio(1);
        st = __builtin_amdgcn_mfma_f32_32x32x16_bf16(k0, q0, st, 0, 0, 0);
        st = __builtin_amdgcn_mfma_f32_32x32x16_bf16(k1, q1, st, 0, 0, 0);
        __builtin_amdgcn_s_setprio(0);
        float p[16];
        #pragma unroll
        for (int r = 0; r < 16; ++r) p[r] = __builtin_amdgcn_exp2f(st[r]);   // raw v_exp_f32
        ls0 += p[0] + p[4] + p[8]  + p[12];
        ls1 += p[1] + p[5] + p[9]  + p[13];
        ls2 += p[2] + p[6] + p[10] + p[14];
        ls3 += p[3] + p[7] + p[11] + p[15];
        unsigned int wpk[8];
        #pragma unroll
        for (int k2 = 0; k2 < 8; ++k2)
            asm("v_cvt_pk_bf16_f32 %0, %1, %2" : "=v"(wpk[k2]) : "v"(p[2*k2]), "v"(p[2*k2+1]));
        asm("v_permlane32_swap_b32 %0, %1" : "+v"(wpk[0]), "+v"(wpk[2]));
        asm("v_permlane32_swap_b32 %0, %1" : "+v"(wpk[1]), "+v"(wpk[3]));
        asm("v_permlane32_swap_b32 %0, %1" : "+v"(wpk[4]), "+v"(wpk[6]));
        asm("v_permlane32_swap_b32 %0, %1" : "+v"(wpk[5]), "+v"(wpk[7]));
        union { bf16x8 v; unsigned int u[4]; } pb0, pb1;
        pb0.u[0] = wpk[0]; pb0.u[1] = wpk[1]; pb0.u[2] = wpk[2]; pb0.u[3] = wpk[3];
        pb1.u[0] = wpk[4]; pb1.u[1] = wpk[5]; pb1.u[2] = wpk[6]; pb1.u[3] = wpk[7];
        __builtin_amdgcn_s_setprio(1);
        oacc = __builtin_amdgcn_mfma_f32_32x32x16_bf16(v0, pb0.v, oacc, 0, 0, 0);
        oacc = __builtin_amdgcn_mfma_f32_32x32x16_bf16(v1, pb1.v, oacc, 0, 0, 0);
        __builtin_amdgcn_s_setprio(0);
    }
    float lsum = (ls0 + ls1) + (ls2 + ls3);

    // ---- 2-way KV merge per head (pure sums)
    if (mh == 1) {
        #pragma unroll
        for (int r = 0; r < 16; ++r) m_lds[h][lane][r] = oacc[r];
        m_lds[h][lane][16] = lsum;
    }
    __syncthreads();
    if (mh == 0) {
        #pragma unroll
        for (int r = 0; r < 16; ++r) oacc[r] += m_lds[h][lane][r];
        lsum += m_lds[h][lane][16];
        lsum += __shfl_xor(lsum, 32);
        float inv = 1.0f / lsum;
        float (*ts)[33] = (float (*)[33]) &m_lds[h][0][0];
        #pragma unroll
        for (int r = 0; r < 16; ++r) {
            int d = (r & 3) + 8 * (r >> 2) + 4 * hi;
            ts[lc][d] = oacc[r] * inv;
        }
    }
    __syncthreads();
    if (mh == 0) {
        float (*ts)[33] = (float (*)[33]) &m_lds[h][0][0];
        const int q = lane >> 4, nl = lane & 15;
        #pragma unroll
        for (int nt = 0; nt < 2; ++nt) {
            union { __hip_bfloat16 h16[8]; uint4 u4; } ov;
            #pragma unroll
            for (int j = 0; j < 8; ++j)
                ov.h16[j] = __float2bfloat16(ts[nt * 16 + nl][q * 8 + j]);
            *(uint4*)(o_lds + (((size_t)nt * 8 + h) * 64 + lane) * 8) = ov.u4;
        }
    }
    __syncthreads();

    // ---- proj phase: wave w = c-tile (0..15); output 32 pixels x 16 channels
    {
        const int ct = w;
        floatx4 acc2[2] = {};
        for (int kks = 0; kks < 8; ++kks) {
            bf16x8 aa = *(const bf16x8*)(wpf + (((size_t)ct * 8 + kks) * 64 + lane) * 8);
            #pragma unroll
            for (int nt = 0; nt < 2; ++nt) {
                bf16x8 bb = *(const bf16x8*)(o_lds + (((size_t)nt * 8 + kks) * 64 + lane) * 8);
                acc2[nt] = __builtin_amdgcn_mfma_f32_16x16x32_bf16(aa, bb, acc2[nt], 0, 0, 0);
            }
        }
        #pragma unroll
        for (int nt = 0; nt < 2; ++nt)
            #pragma unroll
            for (int r = 0; r < 4; ++r) {
                int c = ct * 16 + lg * 4 + r;
                int n = t32 * 32 + nt * 16 + lr;
                size_t idx = ((size_t)b * CC + c) * NPIX + n;
                out[idx] = acc2[nt][r] + bp[c] + x[idx];
            }
    }
}

// ---------------------------------------------------------------- launch
extern "C" void kernel_launch(void* const* d_in, const int* in_sizes, int n_in,
                              void* d_out, int out_size, void* d_ws, size_t ws_size,
                              hipStream_t stream) {
    const float* x      = (const float*)d_in[0];
    const float* gamma  = (const float*)d_in[1];
    const float* beta   = (const float*)d_in[2];
    const float* w_qkv  = (const float*)d_in[3];
    const float* b_qkv  = (const float*)d_in[4];
    const float* w_proj = (const float*)d_in[5];
    const float* b_proj = (const float*)d_in[6];
    float* out = (float*)d_out;

    char* ws = (char*)d_ws;
    __hip_bfloat16* qfb  = (__hip_bfloat16*)(ws);                            // 4 MB
    __hip_bfloat16* kfb  = (__hip_bfloat16*)(ws + (4  << 20));               // 4 MB
    __hip_bfloat16* vfb  = (__hip_bfloat16*)(ws + (8  << 20));               // 4 MB
    __hip_bfloat16* wqf  = (__hip_bfloat16*)(ws + (12 << 20));               // 384 KB frag
    __hip_bfloat16* wpf  = (__hip_bfloat16*)(ws + (12 << 20) + (512 << 10)); // 128 KB frag

    w_prep<<<128, 256, 0, stream>>>(w_qkv, w_proj, wqf, wpf);
    ln_qkv<<<BB * NPIX / 16, 1024, 0, stream>>>(x, gamma, beta, wqf, b_qkv, qfb, kfb, vfb);
    attn_proj<<<BB * 32, 1024, 0, stream>>>(qfb, kfb, vfb, wpf, b_proj, x, out);
}